// Round 1
// baseline (225.709 us; speedup 1.0000x reference)
//
#include <hip/hip_runtime.h>

#define Bn 512
#define Tn 512
#define Cn 64

// Inputs (setup_inputs order):
// 0: emissions (B,T,C) f32   1: tags (B,T) i32   2: mask (B,T) i32
// 3: transitions (C,C) f32   4: start_transitions (C) f32   5: end_transitions (C) f32
// Output: scalar f32 = mean_b(log_denominator - log_numerator)
//
// R6: meet-in-the-middle (R5 structure) with a new per-step dot engine.
//  - alpha broadcast via LDS same-address reads (1 ds_write_b32 + 16 uniform
//    ds_read_b128 per step) instead of 64 v_readlane -> SGPR mirror.
//  - dot computed on float2 pairs (__builtin_elementwise_fma) so the compiler
//    can select full-rate v_pk_fma_f32 (32 packed FMA vs 64 scalar).
//  - renorm (every 4th step) DEFERRED: max/rcp/log chain runs off the critical
//    path; the scale is applied as one multiply at the end of the next step.

typedef float f2 __attribute__((ext_vector_type(2)));
typedef float f4 __attribute__((ext_vector_type(4)));

template <int CTRL>
__device__ __forceinline__ float fmax_dpp(const float v) {
    const int o = __builtin_amdgcn_update_dpp(__float_as_int(v), __float_as_int(v),
                                              CTRL, 0xF, 0xF, false);
    return fmaxf(v, __int_as_float(o));
}

// Validated wave64 max: quad xor1, quad xor2, half-mirror, mirror,
// bcast15, bcast31 -> lane 63 holds the max; readlane broadcasts.
__device__ __forceinline__ float wave_max64(float v) {
    v = fmax_dpp<0x0B1>(v);
    v = fmax_dpp<0x04E>(v);
    v = fmax_dpp<0x141>(v);
    v = fmax_dpp<0x140>(v);
    v = fmax_dpp<0x142>(v);
    v = fmax_dpp<0x143>(v);
    return __int_as_float(__builtin_amdgcn_readlane(__float_as_int(v), 63));
}

// blocks 0..511: forward chain bt (steps t=1..256) + numerator.
// blocks 512..1023: backward chain bt (factors u=511..257, 255 steps).
__global__ __launch_bounds__(64) void crf_half_kernel(
    const float* __restrict__ emissions,
    const int*   __restrict__ tags,
    const int*   __restrict__ mask,
    const float* __restrict__ transitions,
    const float* __restrict__ start_t,
    const float* __restrict__ end_t,
    float*       __restrict__ ws_alpha,   // [Bn][Cn]
    float*       __restrict__ ws_beta,    // [Bn][Cn]
    float*       __restrict__ ws_lsF,     // [Bn]
    float*       __restrict__ ws_lsB,     // [Bn]
    float*       __restrict__ ws_num)     // [Bn]
{
    const int  blk = blockIdx.x;
    const bool fwd = blk < Bn;
    const int  bt  = blk & (Bn - 1);
    const int  j   = threadIdx.x;

    // single wave per block: cross-lane exchange via LDS broadcast, no barrier.
    __shared__ __align__(16) float abuf[2][Cn];

    const float* em  = emissions + (size_t)bt * Tn * Cn + j;
    const float* em0 = emissions + (size_t)bt * Tn * Cn;
    const int*   mk  = mask + bt * Tn;
    const int*   tg  = tags + bt * Tn;

    if (fwd) {
        // ---------------- numerator (joint score), lanes stride over T -----
        float nsum = 0.f;
        int   mcnt = 0;
        for (int t = j; t < Tn; t += 64) {
            const int tag_t = tg[t];
            const int m_t   = mk[t];
            mcnt += m_t;
            if (t >= 1 && m_t) {
                const int tag_p = tg[t - 1];
                nsum += transitions[tag_p * Cn + tag_t] + em0[t * Cn + tag_t];
            }
        }
#pragma unroll
        for (int off = 32; off > 0; off >>= 1) {
            nsum += __shfl_xor(nsum, off, 64);
            mcnt += __shfl_xor(mcnt, off, 64);
        }

        // expT column j, as 32 float2 pairs (pair p = rows 2p,2p+1).
        f2 wv[32];
#pragma unroll
        for (int p = 0; p < 32; ++p) {
            wv[p][0] = __expf(transitions[(2 * p)     * Cn + j]);
            wv[p][1] = __expf(transitions[(2 * p + 1) * Cn + j]);
        }

        // t = 0.
        float lp0 = start_t[j] + em[0];
        const float m0 = wave_max64(lp0);
        float log_scale = m0;
        float a_self = __expf(lp0 - m0);     // lane j holds alpha[j]
        float c_pend = 1.0f;                 // deferred renorm scale

        // Prefetch group 0 (t = 1..4).
        float cur_e[4];
        int   cur_m[4];
#pragma unroll
        for (int k = 0; k < 4; ++k) {
            cur_e[k] = em[(size_t)(1 + k) * Cn];
            cur_m[k] = mk[1 + k];
        }

        for (int g = 0; g < 64; ++g) {       // 64 groups x 4 = 256 steps
            float nxt_e[4];
            int   nxt_m[4];
#pragma unroll
            for (int k = 0; k < 4; ++k) {
                const int t = 4 * g + 5 + k;  // <= 260 < Tn, always valid
                nxt_e[k] = em[(size_t)t * Cn];
                nxt_m[k] = mk[t];
            }
            float ex[4];
#pragma unroll
            for (int k = 0; k < 4; ++k) ex[k] = __expf(cur_e[k]);

#pragma unroll
            for (int k = 0; k < 4; ++k) {
                abuf[k & 1][j] = a_self;      // publish alpha to LDS
                __builtin_amdgcn_wave_barrier();

                const f4* ap = (const f4*)abuf[k & 1];
                f2 facc0 = {0.f, 0.f}, facc1 = {0.f, 0.f};
                f2 facc2 = {0.f, 0.f}, facc3 = {0.f, 0.f};
#pragma unroll
                for (int p = 0; p < 16; ++p) {
                    const f4 q = ap[p];       // uniform addr -> LDS broadcast
                    const f2 lo = {q.x, q.y};
                    const f2 hi = {q.z, q.w};
                    if ((p & 1) == 0) {
                        facc0 = __builtin_elementwise_fma(lo, wv[2 * p],     facc0);
                        facc1 = __builtin_elementwise_fma(hi, wv[2 * p + 1], facc1);
                    } else {
                        facc2 = __builtin_elementwise_fma(lo, wv[2 * p],     facc2);
                        facc3 = __builtin_elementwise_fma(hi, wv[2 * p + 1], facc3);
                    }
                }
                const f2 rr = (facc0 + facc2) + (facc1 + facc3);
                float s = (rr.x + rr.y) * ex[k];
                if (!cur_m[k]) s = a_self;    // frozen step: alpha carries
                if (k == 0) {                 // apply deferred scale exactly once
                    s *= c_pend;
                    c_pend = 1.0f;
                }
                if (k == 3) {                 // renorm every 4th step (deferred)
                    const float mx = wave_max64(s);
                    c_pend = __builtin_amdgcn_rcpf(mx);
                    log_scale += __logf(mx);
                }
                a_self = s;
            }
#pragma unroll
            for (int k = 0; k < 4; ++k) {
                cur_e[k] = nxt_e[k];
                cur_m[k] = nxt_m[k];
            }
        }

        a_self *= c_pend;                     // flush pending scale
        ws_alpha[bt * Cn + j] = a_self;       // alpha_256
        if (j == 0) {
            ws_lsF[bt] = log_scale;
            const int t0 = tg[0];
            const int tl = tg[mcnt - 1];
            ws_num[bt] = start_t[t0] + em0[t0] + nsum + end_t[tl];
        }
    } else {
        // expT ROW j, as 32 float2 pairs (pair p = cols 2p,2p+1; contiguous).
        f2 wv[32];
#pragma unroll
        for (int p = 0; p < 32; ++p) {
            wv[p][0] = __expf(transitions[j * Cn + 2 * p]);
            wv[p][1] = __expf(transitions[j * Cn + 2 * p + 1]);
        }

        // beta_511 = exp(end - max).
        float lp0 = end_t[j];
        const float m0 = wave_max64(lp0);
        float log_scale = m0;
        float b_self = __expf(lp0 - m0);      // lane j holds beta[j]
        float c_pend = 1.0f;

        // Step s applies factor at u = 511 - s (emissions/mask row u).
        // Prefetch group 0: s = 0..3 -> u = 511..508.
        float cur_e[4];
        int   cur_m[4];
#pragma unroll
        for (int k = 0; k < 4; ++k) {
            const int u = Tn - 1 - k;
            cur_e[k] = em[(size_t)u * Cn];
            cur_m[k] = mk[u];
        }

        for (int g = 0; g < 64; ++g) {        // steps s=4g+k, active while s<255
            float nxt_e[4];
            int   nxt_m[4];
#pragma unroll
            for (int k = 0; k < 4; ++k) {
                const int u = Tn - 5 - 4 * g - k;  // >= 252 >= 0, always valid
                nxt_e[k] = em[(size_t)u * Cn];
                nxt_m[k] = mk[u];
            }
            float ex[4];
#pragma unroll
            for (int k = 0; k < 4; ++k) ex[k] = __expf(cur_e[k]);

#pragma unroll
            for (int k = 0; k < 4; ++k) {
                const int s_idx = 4 * g + k;
                if (s_idx < Tn / 2 - 1) {     // 255 steps
                    const float wval = b_self * ex[k];   // e_u[j] * beta[j]
                    abuf[k & 1][j] = wval;
                    __builtin_amdgcn_wave_barrier();

                    const f4* ap = (const f4*)abuf[k & 1];
                    f2 facc0 = {0.f, 0.f}, facc1 = {0.f, 0.f};
                    f2 facc2 = {0.f, 0.f}, facc3 = {0.f, 0.f};
#pragma unroll
                    for (int p = 0; p < 16; ++p) {
                        const f4 q = ap[p];   // uniform addr -> LDS broadcast
                        const f2 lo = {q.x, q.y};
                        const f2 hi = {q.z, q.w};
                        if ((p & 1) == 0) {
                            facc0 = __builtin_elementwise_fma(lo, wv[2 * p],     facc0);
                            facc1 = __builtin_elementwise_fma(hi, wv[2 * p + 1], facc1);
                        } else {
                            facc2 = __builtin_elementwise_fma(lo, wv[2 * p],     facc2);
                            facc3 = __builtin_elementwise_fma(hi, wv[2 * p + 1], facc3);
                        }
                    }
                    const f2 rr = (facc0 + facc2) + (facc1 + facc3);
                    float s = rr.x + rr.y;
                    if (!cur_m[k]) s = b_self;   // frozen step: beta carries
                    if (k == 0) {
                        s *= c_pend;
                        c_pend = 1.0f;
                    }
                    if (k == 3) {
                        const float mx = wave_max64(s);
                        c_pend = __builtin_amdgcn_rcpf(mx);
                        log_scale += __logf(mx);
                    }
                    b_self = s;
                }
            }
#pragma unroll
            for (int k = 0; k < 4; ++k) {
                cur_e[k] = nxt_e[k];
                cur_m[k] = nxt_m[k];
            }
        }

        b_self *= c_pend;                     // flush pending scale
        ws_beta[bt * Cn + j] = b_self;        // beta_256
        if (j == 0) ws_lsB[bt] = log_scale;
    }
}

// Per chain: denom = lsF + lsB + log(sum_i alpha[i]*beta[i]); mean-reduce.
__global__ __launch_bounds__(64) void crf_combine_kernel(
    const float* __restrict__ ws_alpha,
    const float* __restrict__ ws_beta,
    const float* __restrict__ ws_lsF,
    const float* __restrict__ ws_lsB,
    const float* __restrict__ ws_num,
    float*       __restrict__ out)
{
    const int bt = blockIdx.x;
    const int j  = threadIdx.x;
    float v = ws_alpha[bt * Cn + j] * ws_beta[bt * Cn + j];
#pragma unroll
    for (int off = 32; off > 0; off >>= 1) v += __shfl_xor(v, off, 64);
    if (j == 0) {
        const float denom = ws_lsF[bt] + ws_lsB[bt] + __logf(v);
        atomicAdd(out, (denom - ws_num[bt]) * (1.0f / Bn));
    }
}

__global__ void crf_zero_kernel(float* out) { out[0] = 0.f; }

extern "C" void kernel_launch(void* const* d_in, const int* in_sizes, int n_in,
                              void* d_out, int out_size, void* d_ws, size_t ws_size,
                              hipStream_t stream)
{
    const float* emissions   = (const float*)d_in[0];
    const int*   tags        = (const int*)d_in[1];
    const int*   mask        = (const int*)d_in[2];
    const float* transitions = (const float*)d_in[3];
    const float* start_t     = (const float*)d_in[4];
    const float* end_t       = (const float*)d_in[5];

    float* ws       = (float*)d_ws;
    float* ws_alpha = ws;                       // 512*64
    float* ws_beta  = ws_alpha + Bn * Cn;       // 512*64
    float* ws_lsF   = ws_beta + Bn * Cn;        // 512
    float* ws_lsB   = ws_lsF + Bn;              // 512
    float* ws_num   = ws_lsB + Bn;              // 512

    crf_zero_kernel<<<1, 1, 0, stream>>>((float*)d_out);
    crf_half_kernel<<<2 * Bn, Cn, 0, stream>>>(emissions, tags, mask, transitions,
                                               start_t, end_t,
                                               ws_alpha, ws_beta, ws_lsF, ws_lsB, ws_num);
    crf_combine_kernel<<<Bn, Cn, 0, stream>>>(ws_alpha, ws_beta, ws_lsF, ws_lsB,
                                              ws_num, (float*)d_out);
}

// Round 2
// 171.334 us; speedup vs baseline: 1.3174x; 1.3174x over previous
//
#include <hip/hip_runtime.h>

#define Bn 512
#define Tn 512
#define Cn 64

// Inputs (setup_inputs order):
// 0: emissions (B,T,C) f32   1: tags (B,T) i32   2: mask (B,T) i32
// 3: transitions (C,C) f32   4: start_transitions (C) f32   5: end_transitions (C) f32
// Output: scalar f32 = mean_b(log_denominator - log_numerator)
//
// R7: meet-in-the-middle (R5 structure), new per-step dot engine.
//  - __launch_bounds__(64, 1): full VGPR budget. R5's VGPR_Count=52 showed the
//    64 exp(transitions) weights were NOT resident (rematerialized per step).
//    Weights are now pinned into VGPRs via opaque asm.
//  - alpha broadcast via ds_bpermute with uniform index (LDS crossbar, no
//    memory round trip, results in VGPRs, overlaps the FMA chain) instead of
//    64 v_readlane->SGPR (R5) or LDS write/read (R6, regressed).
//  - renorm every 4th step, DEFERRED (validated in R6): max/rcp/log runs off
//    the critical path; scale applied as one multiply in the next step.

template <int CTRL>
__device__ __forceinline__ float fmax_dpp(const float v) {
    const int o = __builtin_amdgcn_update_dpp(__float_as_int(v), __float_as_int(v),
                                              CTRL, 0xF, 0xF, false);
    return fmaxf(v, __int_as_float(o));
}

// Validated wave64 max: quad xor1, quad xor2, half-mirror, mirror,
// bcast15, bcast31 -> lane 63 holds the max; readlane broadcasts.
__device__ __forceinline__ float wave_max64(float v) {
    v = fmax_dpp<0x0B1>(v);
    v = fmax_dpp<0x04E>(v);
    v = fmax_dpp<0x141>(v);
    v = fmax_dpp<0x140>(v);
    v = fmax_dpp<0x142>(v);
    v = fmax_dpp<0x143>(v);
    return __int_as_float(__builtin_amdgcn_readlane(__float_as_int(v), 63));
}

// Broadcast-dot: s = sum_i bcast(lane i of a) * w[i].
// ds_bpermute with uniform byte-index 4*i broadcasts lane i to all lanes.
__device__ __forceinline__ float bcast_dot64(const float a, const float* __restrict__ w) {
    const int ai = __float_as_int(a);
    float acc0 = 0.f, acc1 = 0.f, acc2 = 0.f, acc3 = 0.f;
#pragma unroll
    for (int i = 0; i < Cn; i += 4) {
        const float b0 = __int_as_float(__builtin_amdgcn_ds_bpermute(4 * (i + 0), ai));
        const float b1 = __int_as_float(__builtin_amdgcn_ds_bpermute(4 * (i + 1), ai));
        const float b2 = __int_as_float(__builtin_amdgcn_ds_bpermute(4 * (i + 2), ai));
        const float b3 = __int_as_float(__builtin_amdgcn_ds_bpermute(4 * (i + 3), ai));
        acc0 = fmaf(b0, w[i + 0], acc0);
        acc1 = fmaf(b1, w[i + 1], acc1);
        acc2 = fmaf(b2, w[i + 2], acc2);
        acc3 = fmaf(b3, w[i + 3], acc3);
    }
    return (acc0 + acc1) + (acc2 + acc3);
}

// blocks 0..511: forward chain bt (steps t=1..256) + numerator.
// blocks 512..1023: backward chain bt (factors u=511..257, 255 steps).
__global__ __launch_bounds__(64, 1) void crf_half_kernel(
    const float* __restrict__ emissions,
    const int*   __restrict__ tags,
    const int*   __restrict__ mask,
    const float* __restrict__ transitions,
    const float* __restrict__ start_t,
    const float* __restrict__ end_t,
    float*       __restrict__ ws_alpha,   // [Bn][Cn]
    float*       __restrict__ ws_beta,    // [Bn][Cn]
    float*       __restrict__ ws_lsF,     // [Bn]
    float*       __restrict__ ws_lsB,     // [Bn]
    float*       __restrict__ ws_num)     // [Bn]
{
    const int  blk = blockIdx.x;
    const bool fwd = blk < Bn;
    const int  bt  = blk & (Bn - 1);
    const int  j   = threadIdx.x;

    const float* em  = emissions + (size_t)bt * Tn * Cn + j;
    const float* em0 = emissions + (size_t)bt * Tn * Cn;
    const int*   mk  = mask + bt * Tn;
    const int*   tg  = tags + bt * Tn;

    if (fwd) {
        // ---------------- numerator (joint score), lanes stride over T -----
        float nsum = 0.f;
        int   mcnt = 0;
        for (int t = j; t < Tn; t += 64) {
            const int tag_t = tg[t];
            const int m_t   = mk[t];
            mcnt += m_t;
            if (t >= 1 && m_t) {
                const int tag_p = tg[t - 1];
                nsum += transitions[tag_p * Cn + tag_t] + em0[t * Cn + tag_t];
            }
        }
#pragma unroll
        for (int off = 32; off > 0; off >>= 1) {
            nsum += __shfl_xor(nsum, off, 64);
            mcnt += __shfl_xor(mcnt, off, 64);
        }

        // expT column j in registers, PINNED resident.
        float w[Cn];
#pragma unroll
        for (int i = 0; i < Cn; ++i) w[i] = __expf(transitions[i * Cn + j]);
#pragma unroll
        for (int i = 0; i < Cn; ++i) asm volatile("" : "+v"(w[i]));

        // t = 0.
        float lp0 = start_t[j] + em[0];
        const float m0 = wave_max64(lp0);
        float log_scale = m0;
        float a_self = __expf(lp0 - m0);     // lane j holds alpha[j]
        float c_pend = 1.0f;                 // deferred renorm scale

        // Prefetch group 0 (t = 1..4).
        float cur_e[4];
        int   cur_m[4];
#pragma unroll
        for (int k = 0; k < 4; ++k) {
            cur_e[k] = em[(size_t)(1 + k) * Cn];
            cur_m[k] = mk[1 + k];
        }

        for (int g = 0; g < 64; ++g) {       // 64 groups x 4 = 256 steps
            float nxt_e[4];
            int   nxt_m[4];
#pragma unroll
            for (int k = 0; k < 4; ++k) {
                const int t = 4 * g + 5 + k;  // <= 260 < Tn, always valid
                nxt_e[k] = em[(size_t)t * Cn];
                nxt_m[k] = mk[t];
            }
            float ex[4];
#pragma unroll
            for (int k = 0; k < 4; ++k) ex[k] = __expf(cur_e[k]);

#pragma unroll
            for (int k = 0; k < 4; ++k) {
                float s = bcast_dot64(a_self, w) * ex[k];
                if (!cur_m[k]) s = a_self;    // frozen step: alpha carries
                if (k == 0) {                 // apply deferred scale exactly once
                    s *= c_pend;
                    c_pend = 1.0f;
                }
                if (k == 3) {                 // renorm every 4th step (deferred)
                    const float mx = wave_max64(s);
                    c_pend = __builtin_amdgcn_rcpf(mx);
                    log_scale += __logf(mx);
                }
                a_self = s;
            }
#pragma unroll
            for (int k = 0; k < 4; ++k) {
                cur_e[k] = nxt_e[k];
                cur_m[k] = nxt_m[k];
            }
        }

        a_self *= c_pend;                     // flush pending scale
        ws_alpha[bt * Cn + j] = a_self;       // alpha_256
        if (j == 0) {
            ws_lsF[bt] = log_scale;
            const int t0 = tg[0];
            const int tl = tg[mcnt - 1];
            ws_num[bt] = start_t[t0] + em0[t0] + nsum + end_t[tl];
        }
    } else {
        // expT ROW j in registers (backward dot uses rows), PINNED resident.
        float w[Cn];
#pragma unroll
        for (int i = 0; i < Cn; ++i) w[i] = __expf(transitions[j * Cn + i]);
#pragma unroll
        for (int i = 0; i < Cn; ++i) asm volatile("" : "+v"(w[i]));

        // beta_511 = exp(end - max).
        float lp0 = end_t[j];
        const float m0 = wave_max64(lp0);
        float log_scale = m0;
        float b_self = __expf(lp0 - m0);      // lane j holds beta[j]
        float c_pend = 1.0f;

        // Step s applies factor at u = 511 - s (emissions/mask row u).
        // Prefetch group 0: s = 0..3 -> u = 511..508.
        float cur_e[4];
        int   cur_m[4];
#pragma unroll
        for (int k = 0; k < 4; ++k) {
            const int u = Tn - 1 - k;
            cur_e[k] = em[(size_t)u * Cn];
            cur_m[k] = mk[u];
        }

        for (int g = 0; g < 64; ++g) {        // steps s=4g+k, active while s<255
            float nxt_e[4];
            int   nxt_m[4];
#pragma unroll
            for (int k = 0; k < 4; ++k) {
                const int u = Tn - 5 - 4 * g - k;  // >= 252 >= 0, always valid
                nxt_e[k] = em[(size_t)u * Cn];
                nxt_m[k] = mk[u];
            }
            float ex[4];
#pragma unroll
            for (int k = 0; k < 4; ++k) ex[k] = __expf(cur_e[k]);

#pragma unroll
            for (int k = 0; k < 4; ++k) {
                const int s_idx = 4 * g + k;
                if (s_idx < Tn / 2 - 1) {     // 255 steps
                    const float wval = b_self * ex[k];   // e_u[j] * beta[j]
                    float s = bcast_dot64(wval, w);
                    if (!cur_m[k]) s = b_self;   // frozen step: beta carries
                    if (k == 0) {
                        s *= c_pend;
                        c_pend = 1.0f;
                    }
                    if (k == 3) {
                        const float mx = wave_max64(s);
                        c_pend = __builtin_amdgcn_rcpf(mx);
                        log_scale += __logf(mx);
                    }
                    b_self = s;
                }
            }
#pragma unroll
            for (int k = 0; k < 4; ++k) {
                cur_e[k] = nxt_e[k];
                cur_m[k] = nxt_m[k];
            }
        }

        b_self *= c_pend;                     // flush pending scale
        ws_beta[bt * Cn + j] = b_self;        // beta_256
        if (j == 0) ws_lsB[bt] = log_scale;
    }
}

// Per chain: denom = lsF + lsB + log(sum_i alpha[i]*beta[i]); mean-reduce.
// 32 blocks x 16 waves; one chain per wave; one atomicAdd per block.
__global__ __launch_bounds__(1024) void crf_combine_kernel(
    const float* __restrict__ ws_alpha,
    const float* __restrict__ ws_beta,
    const float* __restrict__ ws_lsF,
    const float* __restrict__ ws_lsB,
    const float* __restrict__ ws_num,
    float*       __restrict__ out)
{
    const int wv = threadIdx.x >> 6;          // wave 0..15
    const int j  = threadIdx.x & 63;
    const int bt = blockIdx.x * 16 + wv;

    __shared__ float part[16];

    float v = ws_alpha[bt * Cn + j] * ws_beta[bt * Cn + j];
#pragma unroll
    for (int off = 32; off > 0; off >>= 1) v += __shfl_xor(v, off, 64);
    if (j == 0) {
        part[wv] = ws_lsF[bt] + ws_lsB[bt] + __logf(v) - ws_num[bt];
    }
    __syncthreads();
    if (threadIdx.x < 64) {
        float p = (j < 16) ? part[j] : 0.f;
#pragma unroll
        for (int off = 32; off > 0; off >>= 1) p += __shfl_xor(p, off, 64);
        if (j == 0) atomicAdd(out, p * (1.0f / Bn));
    }
}

__global__ void crf_zero_kernel(float* out) { out[0] = 0.f; }

extern "C" void kernel_launch(void* const* d_in, const int* in_sizes, int n_in,
                              void* d_out, int out_size, void* d_ws, size_t ws_size,
                              hipStream_t stream)
{
    const float* emissions   = (const float*)d_in[0];
    const int*   tags        = (const int*)d_in[1];
    const int*   mask        = (const int*)d_in[2];
    const float* transitions = (const float*)d_in[3];
    const float* start_t     = (const float*)d_in[4];
    const float* end_t       = (const float*)d_in[5];

    float* ws       = (float*)d_ws;
    float* ws_alpha = ws;                       // 512*64
    float* ws_beta  = ws_alpha + Bn * Cn;       // 512*64
    float* ws_lsF   = ws_beta + Bn * Cn;        // 512
    float* ws_lsB   = ws_lsF + Bn;              // 512
    float* ws_num   = ws_lsB + Bn;              // 512

    crf_zero_kernel<<<1, 1, 0, stream>>>((float*)d_out);
    crf_half_kernel<<<2 * Bn, Cn, 0, stream>>>(emissions, tags, mask, transitions,
                                               start_t, end_t,
                                               ws_alpha, ws_beta, ws_lsF, ws_lsB, ws_num);
    crf_combine_kernel<<<Bn / 16, 1024, 0, stream>>>(ws_alpha, ws_beta, ws_lsF, ws_lsB,
                                                     ws_num, (float*)d_out);
}